// Round 11
// baseline (470.344 us; speedup 1.0000x reference)
//
#include <hip/hip_runtime.h>

typedef unsigned short u16;
typedef unsigned int u32;
typedef __bf16 bf16x8 __attribute__((ext_vector_type(8)));
typedef float f32x4 __attribute__((ext_vector_type(4)));

// ---------------- problem constants ----------------
constexpr int NB = 64, CH3 = 3;
constexpr int PLANES = NB * CH3;          // 192
constexpr int PPIX = 224 * 224;           // 50176 per plane
constexpr int PP = 196;                   // 14x14 pixels per image
constexpr int NPX = NB * PP;              // 12544
constexpr int K2 = 576;                   // padded K for w2 GEMM
constexpr int CIPAD = 1088;               // 1080 padded to 17*64
constexpr int KCONV = 9 * CIPAD;          // 9792 = 153*64
constexpr int BINS = 256;                 // clamped exponent+3-mantissa bins
constexpr int BIN0 = 896;                 // (bits>>20) offset
constexpr int RANK1 = 49674;              // order stats for q=0.99 over 50176
constexpr int RANK2 = 49675;

// ---------------- workspace layout (bytes) ----------------
constexpr size_t OFF_BSUM = 2 * 1024 * 1024;                  // [10][192][196] f32
constexpr size_t SZ_BSUM  = (size_t)10 * PLANES * PP * 4;
constexpr size_t OFF_INVS = OFF_BSUM + SZ_BSUM;               // 1920 f32
constexpr size_t OFF_HBF  = OFF_INVS + 8192;                  // NPX*576 bf16
constexpr size_t OFF_GIT  = OFF_HBF + (size_t)NPX * K2 * 2;   // 64*256*1088 bf16
constexpr size_t SZ_GIT   = (size_t)NB * 256 * CIPAD * 2;     // 35,651,584
constexpr size_t OFF_WGB  = OFF_GIT + SZ_GIT;                 // 640*9792 bf16
constexpr size_t OFF_W2B  = OFF_WGB + (size_t)640 * KCONV * 2;
constexpr size_t OFF_MARR = OFF_W2B + (size_t)640 * K2 * 2;   // NPX*540 f32
constexpr size_t SZ_MARR  = (size_t)NPX * 540 * 4;            // 27,095,040
constexpr size_t OFF_HISTP = OFF_MARR + SZ_MARR;              // [192][14][2560] u16
constexpr size_t SZ_HISTP  = (size_t)PLANES * 14 * 2560 * 2;  // 13,762,560
constexpr size_t OFF_PSUM  = OFF_HISTP + SZ_HISTP;            // [192][14] f32

__device__ __forceinline__ u16 f2bf(float x) {
  union { float f; u32 u; } c; c.f = x;
  u32 r = c.u + 0x7FFFu + ((c.u >> 16) & 1u);
  return (u16)(r >> 16);
}

__device__ __forceinline__ float wred64(float v) {
  v += __shfl_down(v, 32, 64); v += __shfl_down(v, 16, 64);
  v += __shfl_down(v, 8, 64);  v += __shfl_down(v, 4, 64);
  v += __shfl_down(v, 2, 64);  v += __shfl_down(v, 1, 64);
  return v;
}

__device__ __forceinline__ float gred16(float v) {
  v += __shfl_down(v, 8, 16); v += __shfl_down(v, 4, 16);
  v += __shfl_down(v, 2, 16); v += __shfl_down(v, 1, 16);
  return v;
}

__device__ __forceinline__ int hbin(float v) {
  int b = (int)(__float_as_uint(fabsf(v)) >> 20) - BIN0;
  return min(max(b, 0), BINS - 1);
}

__device__ __forceinline__ void cp16(const void* g, void* l) {
  __builtin_amdgcn_global_load_lds((const __attribute__((address_space(1))) u32*)g,
                                   (__attribute__((address_space(3))) u32*)l, 16, 0, 0);
}

// fast tanh/sigmoid via v_exp_f32 (saturates correctly at +-inf)
__device__ __forceinline__ float fast_tanh(float x) {
  return 1.f - 2.f / (1.f + __expf(2.f * x));
}
__device__ __forceinline__ float fast_sigmoid(float x) {
  return 1.f / (1.f + __expf(-x));
}

// raw barrier that is also a compiler memory fence
#define BAR_MEM() asm volatile("s_barrier" ::: "memory")

// ================= merged prep kernel (unchanged from R10) =================
constexpr int RSTRIDE = 10 * 128 + 8;     // bank-staggered replica stride (words)
constexpr int SWT_BLOCKS = 14 * PLANES;   // 2688
constexpr int SHF_WORDS = 4928 + 4 * RSTRIDE + 140 + 4;   // 10224 f32 = 40.9 KB

__global__ __launch_bounds__(256) void prep_kernel(const float* __restrict__ frames,
    const float* __restrict__ wg, const float* __restrict__ w2,
    const float* __restrict__ tclip,
    float* __restrict__ psum, u16* __restrict__ histp, float* __restrict__ bsum,
    u16* __restrict__ wgb, u16* __restrict__ w2b, u16* __restrict__ git)
{
  __shared__ float shf[SHF_WORDS];        // 40.9 KB union -> 3 blocks/CU
  const int bid = blockIdx.x;
  const int t = threadIdx.x;

  if (bid < SWT_BLOCKS) {                 // ================ SWT ================
    float* a1 = shf;                      // 22*224; rows 0..19 become a2 in level 2
    u32* lh = (u32*)(shf + 4928);         // 4*RSTRIDE
    float* csum = shf + 4928 + 4 * RSTRIDE;  // 140
    float* wsum = csum + 140;             // 4
    const int rb = bid % 14, plane = bid / 14;
    const float* Pp = frames + (size_t)plane * PPIX;

    for (int i = t; i < 4 * RSTRIDE; i += 256) lh[i] = 0;
    __syncthreads();

    u32* lhr = &lh[(t & 3) * RSTRIDE];
    const int cell0 = (t >> 4) * 10;
    float ps = 0.f;
    int c2_1 = t + 1; if (c2_1 >= 224) c2_1 -= 224;
    int c2_2 = t + 2; if (c2_2 >= 224) c2_2 -= 224;
    int c2_4 = t + 4; if (c2_4 >= 224) c2_4 -= 224;

    // ---- level 1 (d=1): frames -> a1 rows 0..21, bands rows 0..15 ----
    if (t < 224) {
      float sH = 0.f, sV = 0.f, sD = 0.f;
      float q00 = Pp[(rb * 16) * 224 + t], q01 = Pp[(rb * 16) * 224 + c2_1];
#pragma unroll 2
      for (int r = 0; r < 22; ++r) {
        int gr1 = rb * 16 + r + 1; if (gr1 >= 224) gr1 -= 224;
        float p10 = Pp[gr1 * 224 + t], p11 = Pp[gr1 * 224 + c2_1];
        float sa = q00 + q01, sb = p10 + p11, da = q00 - q01, db = p10 - p11;
        a1[r * 224 + t] = (sa + sb) * 0.5f;
        if (r < 16) {
          float cH = (sa - sb) * 0.5f, cV = (da + db) * 0.5f, cD = (da - db) * 0.5f;
          int bH = hbin(cH), bV = hbin(cV), bD = hbin(cD);
          atomicAdd(&lhr[0 * 128 + (bH >> 1)], 1u << ((bH & 1) * 16));
          atomicAdd(&lhr[1 * 128 + (bV >> 1)], 1u << ((bV & 1) * 16));
          atomicAdd(&lhr[2 * 128 + (bD >> 1)], 1u << ((bD & 1) * 16));
          sH += cH; sV += cV; sD += cD;
          ps += q00;
        }
        q00 = p10; q01 = p11;
      }
      sH = gred16(sH); sV = gred16(sV); sD = gred16(sD);
      if ((t & 15) == 0) { csum[cell0 + 0] = sH; csum[cell0 + 1] = sV; csum[cell0 + 2] = sD; }
    }
    ps = wred64(ps);
    if ((t & 63) == 0) wsum[t >> 6] = ps;
    __syncthreads();                      // a1 complete + wsum visible
    if (t == 0) psum[plane * 14 + rb] = wsum[0] + wsum[1] + wsum[2] + wsum[3];

    // ---- level 2 (d=2): a1 rows r,r+2 -> a2 written OVER a1 row r ----
    {
      float sH = 0.f, sV = 0.f, sD = 0.f;
      float c00 = 0.f, c01 = 0.f, c10 = 0.f, c11 = 0.f;
      if (t < 224) {
        c00 = a1[0 * 224 + t]; c01 = a1[0 * 224 + c2_2];
        c10 = a1[1 * 224 + t]; c11 = a1[1 * 224 + c2_2];
      }
      for (int rp = 0; rp < 10; ++rp) {
        int r = rp * 2;
        float n00 = 0.f, n01 = 0.f, n10 = 0.f, n11 = 0.f;
        if (t < 224) {
          n00 = a1[(r + 2) * 224 + t]; n01 = a1[(r + 2) * 224 + c2_2];
          n10 = a1[(r + 3) * 224 + t]; n11 = a1[(r + 3) * 224 + c2_2];
        }
        __syncthreads();                  // all reads of slots r..r+3 retired
        if (t < 224) {
          float sa0 = c00 + c01, sb0 = n00 + n01, da0 = c00 - c01, db0 = n00 - n01;
          float sa1 = c10 + c11, sb1 = n10 + n11, da1 = c10 - c11, db1 = n10 - n11;
          a1[r * 224 + t] = (sa0 + sb0) * 0.5f;        // a2[r]
          a1[(r + 1) * 224 + t] = (sa1 + sb1) * 0.5f;  // a2[r+1]
          if (rp < 8) {
            float cH0 = (sa0 - sb0) * 0.5f, cV0 = (da0 + db0) * 0.5f, cD0 = (da0 - db0) * 0.5f;
            float cH1 = (sa1 - sb1) * 0.5f, cV1 = (da1 + db1) * 0.5f, cD1 = (da1 - db1) * 0.5f;
            int b0 = hbin(cH0), b1 = hbin(cV0), b2 = hbin(cD0);
            int b3 = hbin(cH1), b4 = hbin(cV1), b5 = hbin(cD1);
            atomicAdd(&lhr[3 * 128 + (b0 >> 1)], 1u << ((b0 & 1) * 16));
            atomicAdd(&lhr[4 * 128 + (b1 >> 1)], 1u << ((b1 & 1) * 16));
            atomicAdd(&lhr[5 * 128 + (b2 >> 1)], 1u << ((b2 & 1) * 16));
            atomicAdd(&lhr[3 * 128 + (b3 >> 1)], 1u << ((b3 & 1) * 16));
            atomicAdd(&lhr[4 * 128 + (b4 >> 1)], 1u << ((b4 & 1) * 16));
            atomicAdd(&lhr[5 * 128 + (b5 >> 1)], 1u << ((b5 & 1) * 16));
            sH += cH0 + cH1; sV += cV0 + cV1; sD += cD0 + cD1;
          }
          c00 = n00; c01 = n01; c10 = n10; c11 = n11;
        }
      }
      if (t < 224) {
        sH = gred16(sH); sV = gred16(sV); sD = gred16(sD);
        if ((t & 15) == 0) { csum[cell0 + 3] = sH; csum[cell0 + 4] = sV; csum[cell0 + 5] = sD; }
      }
    }
    __syncthreads();                      // a2 (slots 0..19) complete

    // ---- level 3 (d=4): a2 rows r,r+4 -> bands + LL, rows 0..15 ----
    if (t < 224) {
      float sH = 0.f, sV = 0.f, sD = 0.f, sA = 0.f;
      float v[4], w[4];
#pragma unroll
      for (int k = 0; k < 4; ++k) { v[k] = a1[k * 224 + t]; w[k] = a1[k * 224 + c2_4]; }
#pragma unroll
      for (int r = 0; r < 16; ++r) {
        float n0 = a1[(r + 4) * 224 + t], n1 = a1[(r + 4) * 224 + c2_4];
        float p00 = v[r & 3], p01 = w[r & 3];
        float sa = p00 + p01, sb = n0 + n1, da = p00 - p01, db = n0 - n1;
        float cA = (sa + sb) * 0.5f;
        float cH = (sa - sb) * 0.5f, cV = (da + db) * 0.5f, cD = (da - db) * 0.5f;
        int bH = hbin(cH), bV = hbin(cV), bD = hbin(cD), bA = hbin(cA);
        atomicAdd(&lhr[6 * 128 + (bH >> 1)], 1u << ((bH & 1) * 16));
        atomicAdd(&lhr[7 * 128 + (bV >> 1)], 1u << ((bV & 1) * 16));
        atomicAdd(&lhr[8 * 128 + (bD >> 1)], 1u << ((bD & 1) * 16));
        atomicAdd(&lhr[9 * 128 + (bA >> 1)], 1u << ((bA & 1) * 16));
        sH += cH; sV += cV; sD += cD; sA += cA;
        v[r & 3] = n0; w[r & 3] = n1;
      }
      sH = gred16(sH); sV = gred16(sV); sD = gred16(sD); sA = gred16(sA);
      if ((t & 15) == 0) {
        csum[cell0 + 6] = sH; csum[cell0 + 7] = sV; csum[cell0 + 8] = sD; csum[cell0 + 9] = sA;
      }
    }
    __syncthreads();

    // ---- flush: plain u16 stores to this block's private hist slice ----
    u16* hp = histp + ((size_t)plane * 14 + rb) * 2560;
    for (int i = t; i < 2560; i += 256) {
      int bg = i >> 8, b = i & 255;
      u32 acc = 0;
#pragma unroll
      for (int rp = 0; rp < 4; ++rp)
        acc += (lh[rp * RSTRIDE + bg * 128 + (b >> 1)] >> ((b & 1) * 16)) & 0xFFFFu;
      hp[i] = (u16)acc;
    }
    if (t < 140) {
      int cell = t / 10, bg = t - cell * 10;
      bsum[((size_t)bg * PLANES + plane) * PP + rb * 14 + cell] = csum[cell * 10 + bg];
    }
  } else if (bid < SWT_BLOCKS + 640) {    // ================ wg pack ================
    const int oc = bid - SWT_BLOCKS;
    if (oc < 540) {
      for (int i = t; i < 9720; i += 256) shf[i] = wg[(size_t)oc * 9720 + i];
    }
    __syncthreads();
    for (int j = t; j < KCONV; j += 256) {
      int kc = j >> 6, i = j & 63;
      int cib = kc / 9, tap = kc - cib * 9;
      int ci = cib * 64 + i;
      float v = (oc < 540 && ci < 1080) ? shf[ci * 9 + tap] : 0.f;
      wgb[(size_t)oc * KCONV + j] = f2bf(v);
    }
  } else if (bid < SWT_BLOCKS + 2080) {   // ================ w2 pack ================
    int tid = (bid - SWT_BLOCKS - 640) * 256 + t;  // < 640*576
    int oc = tid / K2, cc = tid - oc * K2;
    float v = (oc < 540 && cc < 540) ? w2[oc * 540 + cc] : 0.f;
    w2b[tid] = f2bf(v);
  } else if (bid < SWT_BLOCKS + 4169) {   // ============ git halo/pad zero ===========
    constexpr int CPB = 136;              // chunks per border px (1088/8)
    constexpr int CPN = 60 * CPB + 196;   // 8356 chunks per image
    int tid = (bid - SWT_BLOCKS - 2080) * 256 + t;
    if (tid >= NB * CPN) return;
    int n = tid / CPN, rem = tid - n * CPN;
    int y, x, c;
    if (rem < 60 * CPB) {
      int bi = rem / CPB; c = rem - bi * CPB;
      if (bi < 16) { y = 0; x = bi; }
      else if (bi < 32) { y = 15; x = bi - 16; }
      else { int i = bi - 32; y = 1 + (i >> 1); x = (i & 1) * 15; }
    } else {
      int q = rem - 60 * CPB;             // interior pad chunk
      y = 1 + q / 14; x = 1 + q % 14; c = 135;
    }
    f32x4 z = (f32x4){0.f, 0.f, 0.f, 0.f};
    *reinterpret_cast<f32x4*>(&git[((size_t)(n * 256 + y * 16 + x)) * CIPAD + c * 8]) = z;
  } else {                                // =========== t_clip -> git transpose ======
    int local = bid - SWT_BLOCKS - 4169;  // < 2304
    int n = local / 36, rem = local - n * 36;
    int ct = rem >> 2, qt = rem & 3;
    const int tr = t >> 6, tc = t & 63;
#pragma unroll 4
    for (int i = 0; i < 16; ++i) {
      int ci = ct * 64 + i * 4 + tr, q = qt * 64 + tc;
      float v = (ci < 540 && q < 196) ? tclip[((size_t)n * 540 + ci) * 196 + q] : 0.f;
      shf[(i * 4 + tr) * 65 + tc] = v;
    }
    __syncthreads();
#pragma unroll 4
    for (int i = 0; i < 16; ++i) {
      int q = qt * 64 + i * 4 + tr, ci = ct * 64 + tc;
      if (q < 196 && ci < 540) {
        int y = q / 14, x = q - y * 14;
        git[(((size_t)n * 16 + 1 + y) * 16 + 1 + x) * CIPAD + ci] = f2bf(shf[tc * 65 + i * 4 + tr]);
      }
    }
  }
}

// ---------------- quantile from per-rb u16 hist slices (parallel scan) ------------
__global__ __launch_bounds__(256) void quant_kernel(const u16* __restrict__ histp,
    float* __restrict__ invs)
{
  const int g = blockIdx.x;               // g = bg*PLANES + plane
  const int bg = g / PLANES, plane = g - bg * PLANES;
  __shared__ int cum[BINS];
  __shared__ float vv[2];
  const int t = threadIdx.x;
  const u16* hp = histp + (size_t)plane * 14 * 2560 + bg * 256;
  int c = 0;
#pragma unroll
  for (int rb = 0; rb < 14; ++rb) c += hp[rb * 2560 + t];
  cum[t] = c;
  __syncthreads();
  for (int off = 1; off < BINS; off <<= 1) {
    int y = (t >= off) ? cum[t - off] : 0;
    __syncthreads();
    cum[t] += y;
    __syncthreads();
  }
  int inc = cum[t], prev = inc - c;
#pragma unroll
  for (int k = 0; k < 2; ++k) {
    int rank = k ? RANK2 : RANK1;
    if (prev < rank && rank <= inc) {
      float lo = __uint_as_float((u32)(t + BIN0) << 20);
      float hi = __uint_as_float((u32)(t + BIN0 + 1) << 20);
      float fr = ((float)(rank - prev) - 0.5f) / (float)c;
      fr = fminf(fmaxf(fr, 0.f), 1.f);
      vv[k] = lo + (hi - lo) * fr;
    }
  }
  __syncthreads();
  if (t == 0) {
    float s = 0.75f * vv[0] + 0.25f * vv[1];
    invs[g] = 1.f / (s + 1e-4f);
  }
}

// ---------------- GEMM1 (epix fused): h = relu(w1 @ e(bsum,invs) + b1) ------------
__global__ __launch_bounds__(256) void gemm1_kernel(const float* __restrict__ bsum,
    const float* __restrict__ psum, const float* __restrict__ invs,
    const float* __restrict__ w1, const float* __restrict__ b1, u16* __restrict__ hbf)
{
  __shared__ float es[64][33];
  __shared__ float w1s[128][33];
  const int t = threadIdx.x;
  const int px0 = blockIdx.x * 64, oc0 = blockIdx.y * 128;
  for (int i = t; i < 64 * 32; i += 256) {
    int r = i >> 5, cc = i & 31;
    int px = px0 + r, n = px / PP, q = px - n * PP;
    float val = 0.f;
    if (cc < 27) {
      int bg = cc / 3, c = cc - bg * 3;
      int plane = n * 3 + c;
      val = bsum[((size_t)bg * PLANES + plane) * PP + q] * (1.f / 256.f) * invs[bg * PLANES + plane];
    } else if (cc < 30) {
      int c = cc - 27, plane = n * 3 + c;
      float s14 = 0.f;
#pragma unroll
      for (int rb = 0; rb < 14; ++rb) s14 += psum[plane * 14 + rb];
      float mu = s14 * (8.f / 50176.f);
      val = (bsum[((size_t)9 * PLANES + plane) * PP + q] * (1.f / 256.f) - mu) * invs[9 * PLANES + plane];
    }
    es[r][cc] = val;
  }
  for (int i = t; i < 128 * 32; i += 256) {
    int r = i >> 5, cc = i & 31; int oc = oc0 + r;
    w1s[r][cc] = (oc < 540 && cc < 30) ? w1[oc * 30 + cc] : 0.f;
  }
  __syncthreads();
  const int ocl = t & 31, pxl = (t >> 5) * 8;
  float acc[4][8];
#pragma unroll
  for (int i = 0; i < 4; ++i)
#pragma unroll
    for (int j = 0; j < 8; ++j) acc[i][j] = 0.f;
  for (int k = 0; k < 30; ++k) {
    float wv[4], ev[8];
#pragma unroll
    for (int i = 0; i < 4; ++i) wv[i] = w1s[ocl + 32 * i][k];
#pragma unroll
    for (int j = 0; j < 8; ++j) ev[j] = es[pxl + j][k];
#pragma unroll
    for (int i = 0; i < 4; ++i)
#pragma unroll
      for (int j = 0; j < 8; ++j) acc[i][j] += wv[i] * ev[j];
  }
#pragma unroll
  for (int i = 0; i < 4; ++i) {
    int oc = oc0 + ocl + 32 * i;
    if (oc >= 576) continue;
    float bv = (oc < 540) ? b1[oc] : 0.f;
#pragma unroll
    for (int j = 0; j < 8; ++j) {
      int px = px0 + pxl + j;
      float v = (oc < 540) ? fmaxf(acc[i][j] + bv, 0.f) : 0.f;
      hbf[(size_t)px * K2 + oc] = f2bf(v);
    }
  }
}

// ---------------- MFMA GEMM: 256x128 block, 8 waves, TRIPLE-buffered ---------------
// 8 waves (4 px x 2 oc), wave tile 64x64 (inner math identical to the proven R2
// loop). 3 x 48KB LDS buffers (144 KB, 1 block/CU, 8 waves = 2/SIMD -- same
// waves/SIMD as before). stage(kc+2) issues at the TOP of step kc -> prefetch
// depth ~1.8 K-steps (>900cy HBM latency); vmcnt(12) keeps 12 loads in flight.
// 2 barriers per K-step. Grid 245 (=96% of CUs), oc 640/128=5 exact.
// MODE0 = w2 matmul (tanh epilogue -> marr+git), grid dim3(49,5), K=576
// MODE1 = 3x3 conv, full K, fused gate epilogue -> out, grid 245
template <int MODE>
__global__ __launch_bounds__(512) void mfma_gemm_kernel(
    const u16* __restrict__ A, const u16* __restrict__ Bm,
    const float* __restrict__ bias,
    float* __restrict__ marr, u16* __restrict__ git,
    const float* __restrict__ tclip, float* __restrict__ outp)
{
  constexpr int KCPB = (MODE == 1) ? 153 : 9;  // kc steps (BK=64)
  constexpr int BSTRIDE = (MODE == 1) ? KCONV : K2;
  __shared__ u16 smem[73728];                 // 3 x (As 32KB + Bs 16KB) = 144 KB
  const int t = threadIdx.x;
  const int lane = t & 63, wave = t >> 6;
  const int wm = wave & 3, wn = wave >> 2;    // 4 px-waves x 2 oc-waves

  int px0, oc0;
  if constexpr (MODE == 1) {
    // bijective XCD remap (nwg=245=8*30+5): all 5 oc-blocks of a px-tile land on
    // one XCD -> the 5 MB A-panel window is reused from that XCD's L2.
    int orig = blockIdx.x;
    int xcd = orig & 7, off = orig >> 3;
    constexpr int q = 30, r = 5;
    int wg = (xcd < r ? xcd * (q + 1) : r * (q + 1) + (xcd - r) * q) + off;
    int bx = wg / 5, by = wg - bx * 5;
    px0 = bx * 256; oc0 = by * 128;
  } else {
    px0 = blockIdx.x * 256; oc0 = blockIdx.y * 128;
  }

  const u16* aSrc[4];
  const u16* bSrc[2];
  int dstOffA[4], dstOffB[2];
#pragma unroll
  for (int r = 0; r < 4; ++r) {
    int slot = r * 512 + t;
    int row = slot >> 3;                      // 8 threads per 64-elem row
    int gs = ((slot ^ row) & 7) << 3;         // XOR-swizzled 16B group (0 conflicts)
    if constexpr (MODE == 0) {
      aSrc[r] = A + (size_t)(px0 + row) * K2 + gs;
    } else {
      int px = px0 + row;
      int n = px / 196, q2 = px - n * 196;
      int y = q2 / 14, x = q2 - y * 14;
      aSrc[r] = A + (size_t)((n * 16 + y) * 16 + x) * CIPAD + gs;
    }
    dstOffA[r] = (r * 512 + wave * 64) * 8;   // wave-uniform LDS base (elem units)
    if (r < 2) {
      bSrc[r] = Bm + (size_t)(oc0 + row) * BSTRIDE + gs;
      dstOffB[r] = (r * 512 + wave * 64) * 8;
    }
  }

  auto stage = [&](int kcg, int buf) {
    int boff = kcg * 64;
    int aoff;
    if constexpr (MODE == 1) {
      int cib = kcg / 9, tap = kcg - cib * 9; // tap-fastest: A window reused 9x
      int ky = tap / 3, kx = tap - ky * 3;
      aoff = (ky * 16 + kx) * CIPAD + cib * 64;
    } else aoff = boff;
    u16* As = smem + buf * 24576;
    u16* Bs = As + 16384;
#pragma unroll
    for (int r = 0; r < 4; ++r) cp16(aSrc[r] + aoff, As + dstOffA[r]);
#pragma unroll
    for (int r = 0; r < 2; ++r) cp16(bSrc[r] + boff, Bs + dstOffB[r]);
  };

  const int tx = lane & 15, quad = lane >> 4, l7 = lane & 7;
  int rowA[4], rowB[4];
#pragma unroll
  for (int i = 0; i < 4; ++i) {
    rowA[i] = (wm * 64 + i * 16 + tx) * 64;
    rowB[i] = (wn * 64 + i * 16 + tx) * 64;
  }

  f32x4 acc[4][4];
#pragma unroll
  for (int i = 0; i < 4; ++i)
#pragma unroll
    for (int j = 0; j < 4; ++j) acc[i][j] = (f32x4){0.f, 0.f, 0.f, 0.f};

  // prologue: two stages in flight (12 loads/thread)
  stage(0, 0);
  stage(1, 1);
  int cur = 0;                                // kc % 3
  for (int kc = 0; kc < KCPB; ++kc) {
    // issue stage(kc+2) FIRST -> ~1.8 K-steps of latency cover; its buffer
    // ((kc+2)%3) is neither read this step (kc%3) nor next ((kc+1)%3), and the
    // end-of-previous-step barrier retired all reads of it.
    if (kc + 2 < KCPB) stage(kc + 2, (cur + 2 >= 3) ? cur - 1 : cur + 2);
    int rem = KCPB - 1 - kc;
    if (rem >= 2)      { asm volatile("s_waitcnt vmcnt(12)" ::: "memory"); }
    else if (rem == 1) { asm volatile("s_waitcnt vmcnt(6)" ::: "memory"); }
    else               { asm volatile("s_waitcnt vmcnt(0)" ::: "memory"); }
    BAR_MEM();                                // everyone's stage(kc) landed
    const u16* As = smem + cur * 24576;
    const u16* Bs = As + 16384;
#pragma unroll
    for (int ks = 0; ks < 2; ++ks) {
      int goff = (((ks * 4 + quad) ^ l7) << 3);
      bf16x8 af[4], bfr[4];
#pragma unroll
      for (int i = 0; i < 4; ++i) af[i] = *reinterpret_cast<const bf16x8*>(As + rowA[i] + goff);
#pragma unroll
      for (int i = 0; i < 4; ++i) bfr[i] = *reinterpret_cast<const bf16x8*>(Bs + rowB[i] + goff);
      __builtin_amdgcn_s_setprio(1);
#pragma unroll
      for (int i = 0; i < 4; ++i)
#pragma unroll
        for (int j = 0; j < 4; ++j)
          acc[i][j] = __builtin_amdgcn_mfma_f32_16x16x32_bf16(af[i], bfr[j], acc[i][j], 0, 0, 0);
      __builtin_amdgcn_s_setprio(0);
    }
    BAR_MEM();                                // all reads of cur retired
    cur = (cur + 1 >= 3) ? 0 : cur + 1;
  }

#pragma unroll
  for (int j = 0; j < 4; ++j) {
    int oc = oc0 + wn * 64 + j * 16 + tx;
    if (oc >= 540) continue;
    float bv = bias[oc];
#pragma unroll
    for (int i = 0; i < 4; ++i) {
      f32x4 v = acc[i][j];
      int px = px0 + wm * 64 + i * 16 + quad * 4;
      int n = px / 196, q2 = px - n * 196;    // 196 % 4 == 0: quad never crosses image
      size_t idx = ((size_t)(n * 540 + oc)) * 196 + q2;
      if constexpr (MODE == 0) {
#pragma unroll
        for (int r = 0; r < 4; ++r) {
          float val = fast_tanh(v[r] + bv);
          marr[idx + r] = val;
          int qq = q2 + r;
          int y = qq / 14, x = qq - y * 14;
          git[((n * 16 + 1 + y) * 16 + 1 + x) * CIPAD + 540 + oc] = f2bf(val);
        }
      } else {
        f32x4 mv = *reinterpret_cast<const f32x4*>(marr + idx);
        f32x4 tv = *reinterpret_cast<const f32x4*>(tclip + idx);
        f32x4 res;
#pragma unroll
        for (int r = 0; r < 4; ++r) {
          res[r] = tv[r] + mv[r] * fast_sigmoid(v[r] + bv);
        }
        *reinterpret_cast<f32x4*>(outp + idx) = res;
      }
    }
  }
}

// ---------------- launcher ----------------
extern "C" void kernel_launch(void* const* d_in, const int* in_sizes, int n_in,
                              void* d_out, int out_size, void* d_ws, size_t ws_size,
                              hipStream_t stream)
{
  const float* frames = (const float*)d_in[0];
  const float* t_clip = (const float*)d_in[1];
  const float* w1 = (const float*)d_in[2];
  const float* b1 = (const float*)d_in[3];
  const float* w2 = (const float*)d_in[4];
  const float* b2 = (const float*)d_in[5];
  const float* wg = (const float*)d_in[6];
  const float* bg = (const float*)d_in[7];
  float* out = (float*)d_out;
  char* ws = (char*)d_ws;

  float* BSUM = (float*)(ws + OFF_BSUM);
  float* INVS = (float*)(ws + OFF_INVS);
  u16* HBF = (u16*)(ws + OFF_HBF);
  u16* GIT = (u16*)(ws + OFF_GIT);
  u16* WGB = (u16*)(ws + OFF_WGB);
  u16* W2B = (u16*)(ws + OFF_W2B);
  float* MARR = (float*)(ws + OFF_MARR);
  u16* HISTP = (u16*)(ws + OFF_HISTP);
  float* PSUM = (float*)(ws + OFF_PSUM);

  // merged prep: SWT (critical path, blocks first) + packs + halo + transpose.
  prep_kernel<<<SWT_BLOCKS + 6473, 256, 0, stream>>>(
      frames, wg, w2, t_clip, PSUM, HISTP, BSUM, WGB, W2B, GIT);

  quant_kernel<<<1920, 256, 0, stream>>>(HISTP, INVS);

  // MLP (epix fused into gemm1; tanh -> marr+git), then conv + fused gate -> out
  gemm1_kernel<<<dim3(196, 5), 256, 0, stream>>>(BSUM, PSUM, INVS, w1, b1, HBF);
  mfma_gemm_kernel<0><<<dim3(49, 5), 512, 0, stream>>>(HBF, W2B, b2, MARR, GIT, nullptr, nullptr);
  mfma_gemm_kernel<1><<<245, 512, 0, stream>>>(GIT, WGB, bg, MARR, nullptr, t_clip, out);
}

// Round 13
// 429.464 us; speedup vs baseline: 1.0952x; 1.0952x over previous
//
#include <hip/hip_runtime.h>

typedef unsigned short u16;
typedef unsigned int u32;
typedef __bf16 bf16x8 __attribute__((ext_vector_type(8)));
typedef float f32x4 __attribute__((ext_vector_type(4)));
typedef u16 u16x4 __attribute__((ext_vector_type(4)));

// ---------------- problem constants ----------------
constexpr int NB = 64, CH3 = 3;
constexpr int PLANES = NB * CH3;          // 192
constexpr int PPIX = 224 * 224;           // 50176 per plane
constexpr int PP = 196;                   // 14x14 pixels per image
constexpr int NPX = NB * PP;              // 12544
constexpr int K2 = 576;                   // padded K for w2 GEMM
constexpr int CIPAD = 1088;               // 1080 padded to 17*64
constexpr int KCONV = 9 * CIPAD;          // 9792 = 153*64
constexpr int BINS = 256;                 // clamped exponent+3-mantissa bins
constexpr int BIN0 = 896;                 // (bits>>20) offset
constexpr int RANK1 = 49674;              // order stats for q=0.99 over 50176
constexpr int RANK2 = 49675;

// ---------------- workspace layout (bytes) ----------------
constexpr size_t OFF_BSUM = 2 * 1024 * 1024;                  // [10][192][196] f32
constexpr size_t SZ_BSUM  = (size_t)10 * PLANES * PP * 4;
constexpr size_t OFF_INVS = OFF_BSUM + SZ_BSUM;               // 1920 f32
constexpr size_t OFF_HBF  = OFF_INVS + 8192;                  // NPX*576 bf16
constexpr size_t OFF_GIT  = OFF_HBF + (size_t)NPX * K2 * 2;   // 64*256*1088 bf16
constexpr size_t SZ_GIT   = (size_t)NB * 256 * CIPAD * 2;     // 35,651,584
constexpr size_t OFF_WGB  = OFF_GIT + SZ_GIT;                 // 640*9792 bf16
constexpr size_t OFF_W2B  = OFF_WGB + (size_t)640 * KCONV * 2;
constexpr size_t OFF_MARR = OFF_W2B + (size_t)640 * K2 * 2;   // NPX*540 bf16
constexpr size_t SZ_MARR  = (size_t)NPX * 540 * 2;            // 13,547,520
constexpr size_t OFF_HISTP = OFF_MARR + SZ_MARR;              // [192][14][2560] u16
constexpr size_t SZ_HISTP  = (size_t)PLANES * 14 * 2560 * 2;  // 13,762,560
constexpr size_t OFF_PSUM  = OFF_HISTP + SZ_HISTP;            // [192][14] f32

__device__ __forceinline__ u16 f2bf(float x) {
  union { float f; u32 u; } c; c.f = x;
  u32 r = c.u + 0x7FFFu + ((c.u >> 16) & 1u);
  return (u16)(r >> 16);
}

__device__ __forceinline__ float bf2f(u16 b) {
  return __uint_as_float((u32)b << 16);
}

__device__ __forceinline__ float wred64(float v) {
  v += __shfl_down(v, 32, 64); v += __shfl_down(v, 16, 64);
  v += __shfl_down(v, 8, 64);  v += __shfl_down(v, 4, 64);
  v += __shfl_down(v, 2, 64);  v += __shfl_down(v, 1, 64);
  return v;
}

__device__ __forceinline__ float gred16(float v) {
  v += __shfl_down(v, 8, 16); v += __shfl_down(v, 4, 16);
  v += __shfl_down(v, 2, 16); v += __shfl_down(v, 1, 16);
  return v;
}

__device__ __forceinline__ int hbin(float v) {
  int b = (int)(__float_as_uint(fabsf(v)) >> 20) - BIN0;
  return min(max(b, 0), BINS - 1);
}

__device__ __forceinline__ void cp16(const void* g, void* l) {
  __builtin_amdgcn_global_load_lds((const __attribute__((address_space(1))) u32*)g,
                                   (__attribute__((address_space(3))) u32*)l, 16, 0, 0);
}

// fast tanh/sigmoid via v_exp_f32 (saturates correctly at +-inf)
__device__ __forceinline__ float fast_tanh(float x) {
  return 1.f - 2.f / (1.f + __expf(2.f * x));
}
__device__ __forceinline__ float fast_sigmoid(float x) {
  return 1.f / (1.f + __expf(-x));
}

// raw barrier that is also a compiler memory fence
#define BAR_MEM() asm volatile("s_barrier" ::: "memory")

// ================= merged prep kernel (R10-proven) =================
constexpr int RSTRIDE = 10 * 128 + 8;     // bank-staggered replica stride (words)
constexpr int SWT_BLOCKS = 14 * PLANES;   // 2688
constexpr int SHF_WORDS = 4928 + 4 * RSTRIDE + 140 + 4;   // 10224 f32 = 40.9 KB

__global__ __launch_bounds__(256) void prep_kernel(const float* __restrict__ frames,
    const float* __restrict__ wg, const float* __restrict__ w2,
    const float* __restrict__ tclip,
    float* __restrict__ psum, u16* __restrict__ histp, float* __restrict__ bsum,
    u16* __restrict__ wgb, u16* __restrict__ w2b, u16* __restrict__ git)
{
  __shared__ float shf[SHF_WORDS];        // 40.9 KB union -> 3 blocks/CU
  const int bid = blockIdx.x;
  const int t = threadIdx.x;

  if (bid < SWT_BLOCKS) {                 // ================ SWT ================
    float* a1 = shf;                      // 22*224; rows 0..19 become a2 in level 2
    u32* lh = (u32*)(shf + 4928);         // 4*RSTRIDE
    float* csum = shf + 4928 + 4 * RSTRIDE;  // 140
    float* wsum = csum + 140;             // 4
    const int rb = bid % 14, plane = bid / 14;
    const float* Pp = frames + (size_t)plane * PPIX;

    for (int i = t; i < 4 * RSTRIDE; i += 256) lh[i] = 0;
    __syncthreads();

    u32* lhr = &lh[(t & 3) * RSTRIDE];
    const int cell0 = (t >> 4) * 10;
    float ps = 0.f;
    int c2_1 = t + 1; if (c2_1 >= 224) c2_1 -= 224;
    int c2_2 = t + 2; if (c2_2 >= 224) c2_2 -= 224;
    int c2_4 = t + 4; if (c2_4 >= 224) c2_4 -= 224;

    // ---- level 1 (d=1): frames -> a1 rows 0..21, bands rows 0..15 ----
    if (t < 224) {
      float sH = 0.f, sV = 0.f, sD = 0.f;
      float q00 = Pp[(rb * 16) * 224 + t], q01 = Pp[(rb * 16) * 224 + c2_1];
#pragma unroll 2
      for (int r = 0; r < 22; ++r) {
        int gr1 = rb * 16 + r + 1; if (gr1 >= 224) gr1 -= 224;
        float p10 = Pp[gr1 * 224 + t], p11 = Pp[gr1 * 224 + c2_1];
        float sa = q00 + q01, sb = p10 + p11, da = q00 - q01, db = p10 - p11;
        a1[r * 224 + t] = (sa + sb) * 0.5f;
        if (r < 16) {
          float cH = (sa - sb) * 0.5f, cV = (da + db) * 0.5f, cD = (da - db) * 0.5f;
          int bH = hbin(cH), bV = hbin(cV), bD = hbin(cD);
          atomicAdd(&lhr[0 * 128 + (bH >> 1)], 1u << ((bH & 1) * 16));
          atomicAdd(&lhr[1 * 128 + (bV >> 1)], 1u << ((bV & 1) * 16));
          atomicAdd(&lhr[2 * 128 + (bD >> 1)], 1u << ((bD & 1) * 16));
          sH += cH; sV += cV; sD += cD;
          ps += q00;
        }
        q00 = p10; q01 = p11;
      }
      sH = gred16(sH); sV = gred16(sV); sD = gred16(sD);
      if ((t & 15) == 0) { csum[cell0 + 0] = sH; csum[cell0 + 1] = sV; csum[cell0 + 2] = sD; }
    }
    ps = wred64(ps);
    if ((t & 63) == 0) wsum[t >> 6] = ps;
    __syncthreads();                      // a1 complete + wsum visible
    if (t == 0) psum[plane * 14 + rb] = wsum[0] + wsum[1] + wsum[2] + wsum[3];

    // ---- level 2 (d=2): a1 rows r,r+2 -> a2 written OVER a1 row r ----
    {
      float sH = 0.f, sV = 0.f, sD = 0.f;
      float c00 = 0.f, c01 = 0.f, c10 = 0.f, c11 = 0.f;
      if (t < 224) {
        c00 = a1[0 * 224 + t]; c01 = a1[0 * 224 + c2_2];
        c10 = a1[1 * 224 + t]; c11 = a1[1 * 224 + c2_2];
      }
      for (int rp = 0; rp < 10; ++rp) {
        int r = rp * 2;
        float n00 = 0.f, n01 = 0.f, n10 = 0.f, n11 = 0.f;
        if (t < 224) {
          n00 = a1[(r + 2) * 224 + t]; n01 = a1[(r + 2) * 224 + c2_2];
          n10 = a1[(r + 3) * 224 + t]; n11 = a1[(r + 3) * 224 + c2_2];
        }
        __syncthreads();                  // all reads of slots r..r+3 retired
        if (t < 224) {
          float sa0 = c00 + c01, sb0 = n00 + n01, da0 = c00 - c01, db0 = n00 - n01;
          float sa1 = c10 + c11, sb1 = n10 + n11, da1 = c10 - c11, db1 = n10 - n11;
          a1[r * 224 + t] = (sa0 + sb0) * 0.5f;        // a2[r]
          a1[(r + 1) * 224 + t] = (sa1 + sb1) * 0.5f;  // a2[r+1]
          if (rp < 8) {
            float cH0 = (sa0 - sb0) * 0.5f, cV0 = (da0 + db0) * 0.5f, cD0 = (da0 - db0) * 0.5f;
            float cH1 = (sa1 - sb1) * 0.5f, cV1 = (da1 + db1) * 0.5f, cD1 = (da1 - db1) * 0.5f;
            int b0 = hbin(cH0), b1 = hbin(cV0), b2 = hbin(cD0);
            int b3 = hbin(cH1), b4 = hbin(cV1), b5 = hbin(cD1);
            atomicAdd(&lhr[3 * 128 + (b0 >> 1)], 1u << ((b0 & 1) * 16));
            atomicAdd(&lhr[4 * 128 + (b1 >> 1)], 1u << ((b1 & 1) * 16));
            atomicAdd(&lhr[5 * 128 + (b2 >> 1)], 1u << ((b2 & 1) * 16));
            atomicAdd(&lhr[3 * 128 + (b3 >> 1)], 1u << ((b3 & 1) * 16));
            atomicAdd(&lhr[4 * 128 + (b4 >> 1)], 1u << ((b4 & 1) * 16));
            atomicAdd(&lhr[5 * 128 + (b5 >> 1)], 1u << ((b5 & 1) * 16));
            sH += cH0 + cH1; sV += cV0 + cV1; sD += cD0 + cD1;
          }
          c00 = n00; c01 = n01; c10 = n10; c11 = n11;
        }
      }
      if (t < 224) {
        sH = gred16(sH); sV = gred16(sV); sD = gred16(sD);
        if ((t & 15) == 0) { csum[cell0 + 3] = sH; csum[cell0 + 4] = sV; csum[cell0 + 5] = sD; }
      }
    }
    __syncthreads();                      // a2 (slots 0..19) complete

    // ---- level 3 (d=4): a2 rows r,r+4 -> bands + LL, rows 0..15 ----
    if (t < 224) {
      float sH = 0.f, sV = 0.f, sD = 0.f, sA = 0.f;
      float v[4], w[4];
#pragma unroll
      for (int k = 0; k < 4; ++k) { v[k] = a1[k * 224 + t]; w[k] = a1[k * 224 + c2_4]; }
#pragma unroll
      for (int r = 0; r < 16; ++r) {
        float n0 = a1[(r + 4) * 224 + t], n1 = a1[(r + 4) * 224 + c2_4];
        float p00 = v[r & 3], p01 = w[r & 3];
        float sa = p00 + p01, sb = n0 + n1, da = p00 - p01, db = n0 - n1;
        float cA = (sa + sb) * 0.5f;
        float cH = (sa - sb) * 0.5f, cV = (da + db) * 0.5f, cD = (da - db) * 0.5f;
        int bH = hbin(cH), bV = hbin(cV), bD = hbin(cD), bA = hbin(cA);
        atomicAdd(&lhr[6 * 128 + (bH >> 1)], 1u << ((bH & 1) * 16));
        atomicAdd(&lhr[7 * 128 + (bV >> 1)], 1u << ((bV & 1) * 16));
        atomicAdd(&lhr[8 * 128 + (bD >> 1)], 1u << ((bD & 1) * 16));
        atomicAdd(&lhr[9 * 128 + (bA >> 1)], 1u << ((bA & 1) * 16));
        sH += cH; sV += cV; sD += cD; sA += cA;
        v[r & 3] = n0; w[r & 3] = n1;
      }
      sH = gred16(sH); sV = gred16(sV); sD = gred16(sD); sA = gred16(sA);
      if ((t & 15) == 0) {
        csum[cell0 + 6] = sH; csum[cell0 + 7] = sV; csum[cell0 + 8] = sD; csum[cell0 + 9] = sA;
      }
    }
    __syncthreads();

    // ---- flush: plain u16 stores to this block's private hist slice ----
    u16* hp = histp + ((size_t)plane * 14 + rb) * 2560;
    for (int i = t; i < 2560; i += 256) {
      int bg = i >> 8, b = i & 255;
      u32 acc = 0;
#pragma unroll
      for (int rp = 0; rp < 4; ++rp)
        acc += (lh[rp * RSTRIDE + bg * 128 + (b >> 1)] >> ((b & 1) * 16)) & 0xFFFFu;
      hp[i] = (u16)acc;
    }
    if (t < 140) {
      int cell = t / 10, bg = t - cell * 10;
      bsum[((size_t)bg * PLANES + plane) * PP + rb * 14 + cell] = csum[cell * 10 + bg];
    }
  } else if (bid < SWT_BLOCKS + 640) {    // ================ wg pack ================
    const int oc = bid - SWT_BLOCKS;
    if (oc < 540) {
      for (int i = t; i < 9720; i += 256) shf[i] = wg[(size_t)oc * 9720 + i];
    }
    __syncthreads();
    for (int j = t; j < KCONV; j += 256) {
      int kc = j >> 6, i = j & 63;
      int cib = kc / 9, tap = kc - cib * 9;
      int ci = cib * 64 + i;
      float v = (oc < 540 && ci < 1080) ? shf[ci * 9 + tap] : 0.f;
      wgb[(size_t)oc * KCONV + j] = f2bf(v);
    }
  } else if (bid < SWT_BLOCKS + 2080) {   // ================ w2 pack ================
    int tid = (bid - SWT_BLOCKS - 640) * 256 + t;  // < 640*576
    int oc = tid / K2, cc = tid - oc * K2;
    float v = (oc < 540 && cc < 540) ? w2[oc * 540 + cc] : 0.f;
    w2b[tid] = f2bf(v);
  } else if (bid < SWT_BLOCKS + 4169) {   // ============ git halo/pad zero ===========
    constexpr int CPB = 136;              // chunks per border px (1088/8)
    constexpr int CPN = 60 * CPB + 196;   // 8356 chunks per image
    int tid = (bid - SWT_BLOCKS - 2080) * 256 + t;
    if (tid >= NB * CPN) return;
    int n = tid / CPN, rem = tid - n * CPN;
    int y, x, c;
    if (rem < 60 * CPB) {
      int bi = rem / CPB; c = rem - bi * CPB;
      if (bi < 16) { y = 0; x = bi; }
      else if (bi < 32) { y = 15; x = bi - 16; }
      else { int i = bi - 32; y = 1 + (i >> 1); x = (i & 1) * 15; }
    } else {
      int q = rem - 60 * CPB;             // interior pad chunk
      y = 1 + q / 14; x = 1 + q % 14; c = 135;
    }
    f32x4 z = (f32x4){0.f, 0.f, 0.f, 0.f};
    *reinterpret_cast<f32x4*>(&git[((size_t)(n * 256 + y * 16 + x)) * CIPAD + c * 8]) = z;
  } else {                                // =========== t_clip -> git transpose ======
    int local = bid - SWT_BLOCKS - 4169;  // < 2304
    int n = local / 36, rem = local - n * 36;
    int ct = rem >> 2, qt = rem & 3;
    const int tr = t >> 6, tc = t & 63;
#pragma unroll 4
    for (int i = 0; i < 16; ++i) {
      int ci = ct * 64 + i * 4 + tr, q = qt * 64 + tc;
      float v = (ci < 540 && q < 196) ? tclip[((size_t)n * 540 + ci) * 196 + q] : 0.f;
      shf[(i * 4 + tr) * 65 + tc] = v;
    }
    __syncthreads();
#pragma unroll 4
    for (int i = 0; i < 16; ++i) {
      int q = qt * 64 + i * 4 + tr, ci = ct * 64 + tc;
      if (q < 196 && ci < 540) {
        int y = q / 14, x = q - y * 14;
        git[(((size_t)n * 16 + 1 + y) * 16 + 1 + x) * CIPAD + ci] = f2bf(shf[tc * 65 + i * 4 + tr]);
      }
    }
  }
}

// ---------------- quantile from per-rb u16 hist slices (parallel scan) ------------
__global__ __launch_bounds__(256) void quant_kernel(const u16* __restrict__ histp,
    float* __restrict__ invs)
{
  const int g = blockIdx.x;               // g = bg*PLANES + plane
  const int bg = g / PLANES, plane = g - bg * PLANES;
  __shared__ int cum[BINS];
  __shared__ float vv[2];
  const int t = threadIdx.x;
  const u16* hp = histp + (size_t)plane * 14 * 2560 + bg * 256;
  int c = 0;
#pragma unroll
  for (int rb = 0; rb < 14; ++rb) c += hp[rb * 2560 + t];
  cum[t] = c;
  __syncthreads();
  for (int off = 1; off < BINS; off <<= 1) {
    int y = (t >= off) ? cum[t - off] : 0;
    __syncthreads();
    cum[t] += y;
    __syncthreads();
  }
  int inc = cum[t], prev = inc - c;
#pragma unroll
  for (int k = 0; k < 2; ++k) {
    int rank = k ? RANK2 : RANK1;
    if (prev < rank && rank <= inc) {
      float lo = __uint_as_float((u32)(t + BIN0) << 20);
      float hi = __uint_as_float((u32)(t + BIN0 + 1) << 20);
      float fr = ((float)(rank - prev) - 0.5f) / (float)c;
      fr = fminf(fmaxf(fr, 0.f), 1.f);
      vv[k] = lo + (hi - lo) * fr;
    }
  }
  __syncthreads();
  if (t == 0) {
    float s = 0.75f * vv[0] + 0.25f * vv[1];
    invs[g] = 1.f / (s + 1e-4f);
  }
}

// ---------------- GEMM1 (epix fused): h = relu(w1 @ e(bsum,invs) + b1) ------------
__global__ __launch_bounds__(256) void gemm1_kernel(const float* __restrict__ bsum,
    const float* __restrict__ psum, const float* __restrict__ invs,
    const float* __restrict__ w1, const float* __restrict__ b1, u16* __restrict__ hbf)
{
  __shared__ float es[64][33];
  __shared__ float w1s[128][33];
  const int t = threadIdx.x;
  const int px0 = blockIdx.x * 64, oc0 = blockIdx.y * 128;
  for (int i = t; i < 64 * 32; i += 256) {
    int r = i >> 5, cc = i & 31;
    int px = px0 + r, n = px / PP, q = px - n * PP;
    float val = 0.f;
    if (cc < 27) {
      int bg = cc / 3, c = cc - bg * 3;
      int plane = n * 3 + c;
      val = bsum[((size_t)bg * PLANES + plane) * PP + q] * (1.f / 256.f) * invs[bg * PLANES + plane];
    } else if (cc < 30) {
      int c = cc - 27, plane = n * 3 + c;
      float s14 = 0.f;
#pragma unroll
      for (int rb = 0; rb < 14; ++rb) s14 += psum[plane * 14 + rb];
      float mu = s14 * (8.f / 50176.f);
      val = (bsum[((size_t)9 * PLANES + plane) * PP + q] * (1.f / 256.f) - mu) * invs[9 * PLANES + plane];
    }
    es[r][cc] = val;
  }
  for (int i = t; i < 128 * 32; i += 256) {
    int r = i >> 5, cc = i & 31; int oc = oc0 + r;
    w1s[r][cc] = (oc < 540 && cc < 30) ? w1[oc * 30 + cc] : 0.f;
  }
  __syncthreads();
  const int ocl = t & 31, pxl = (t >> 5) * 8;
  float acc[4][8];
#pragma unroll
  for (int i = 0; i < 4; ++i)
#pragma unroll
    for (int j = 0; j < 8; ++j) acc[i][j] = 0.f;
  for (int k = 0; k < 30; ++k) {
    float wv[4], ev[8];
#pragma unroll
    for (int i = 0; i < 4; ++i) wv[i] = w1s[ocl + 32 * i][k];
#pragma unroll
    for (int j = 0; j < 8; ++j) ev[j] = es[pxl + j][k];
#pragma unroll
    for (int i = 0; i < 4; ++i)
#pragma unroll
      for (int j = 0; j < 8; ++j) acc[i][j] += wv[i] * ev[j];
  }
#pragma unroll
  for (int i = 0; i < 4; ++i) {
    int oc = oc0 + ocl + 32 * i;
    if (oc >= 576) continue;
    float bv = (oc < 540) ? b1[oc] : 0.f;
#pragma unroll
    for (int j = 0; j < 8; ++j) {
      int px = px0 + pxl + j;
      float v = (oc < 540) ? fmaxf(acc[i][j] + bv, 0.f) : 0.f;
      hbf[(size_t)px * K2 + oc] = f2bf(v);
    }
  }
}

// ---------------- MFMA GEMM, BK=64 double-buffered, COUNTED vmcnt pipeline --------
// (R10-proven config: 128x128 block tile, 64x64 wave tile, 2x32KB LDS, 2 blocks/CU.
// Three deviations from this structure regressed: R3 96KB/1blk, R6 B-only-LDS,
// R11 144KB-tbuf/8-wave. Do not deviate without the full 8-phase interleave.)
// T4: vmcnt(8) keeps the next tile's 8 global_load_lds in flight across the
// 32-MFMA compute phase. T5: setprio around the MFMA cluster.
// MODE0 = w2 matmul (tanh epilogue -> bf16 marr + git), grid dim3(98,5), K=576
// MODE1 = 3x3 conv, full K, fused gate epilogue -> out, grid 490
template <int MODE>
__global__ __launch_bounds__(256) void mfma_gemm_kernel(
    const u16* __restrict__ A, const u16* __restrict__ Bm,
    const float* __restrict__ bias,
    u16* __restrict__ marr, u16* __restrict__ git,
    const float* __restrict__ tclip, float* __restrict__ outp)
{
  constexpr int KCPB = (MODE == 1) ? 153 : 9;  // kc steps (BK=64)
  constexpr int BSTRIDE = (MODE == 1) ? KCONV : K2;
  __shared__ u16 smem[32768];                 // 2 x (As 16KB + Bs 16KB)
  const int t = threadIdx.x;
  const int lane = t & 63, wave = t >> 6;
  const int wm = wave & 1, wn = wave >> 1;

  int px0, oc0;
  if constexpr (MODE == 1) {
    // bijective XCD remap (nwg=490=8*61+2): all 5 oc-blocks of a px-tile land on
    // one XCD -> the 2.5 MB A-panel is reused from that XCD's L2.
    int orig = blockIdx.x;
    int xcd = orig & 7, off = orig >> 3;
    constexpr int q = 61, r = 2;
    int wg = (xcd < r ? xcd * (q + 1) : r * (q + 1) + (xcd - r) * q) + off;
    int bx = wg / 5, by = wg - bx * 5;
    px0 = bx * 128; oc0 = by * 128;
  } else {
    px0 = blockIdx.x * 128; oc0 = blockIdx.y * 128;
  }

  const u16* aSrc[4];
  const u16* bSrc[4];
  int dstOff[4];
#pragma unroll
  for (int r = 0; r < 4; ++r) {
    int slot = r * 256 + t;
    int row = slot >> 3;
    int gs = ((slot ^ row) & 7) << 3;         // XOR-swizzled 16B group (0 conflicts)
    if constexpr (MODE == 0) {
      aSrc[r] = A + (size_t)(px0 + row) * K2 + gs;
    } else {
      int px = px0 + row;
      int n = px / 196, q2 = px - n * 196;
      int y = q2 / 14, x = q2 - y * 14;
      aSrc[r] = A + (size_t)((n * 16 + y) * 16 + x) * CIPAD + gs;
    }
    bSrc[r] = Bm + (size_t)(oc0 + row) * BSTRIDE + gs;
    dstOff[r] = (r * 256 + wave * 64) * 8;    // wave-uniform LDS base (u16 units)
  }

  auto stage = [&](int kcg, int buf) {
    int boff = kcg * 64;
    int aoff;
    if constexpr (MODE == 1) {
      int cib = kcg / 9, tap = kcg - cib * 9; // tap-fastest: A window reused 9x
      int ky = tap / 3, kx = tap - ky * 3;
      aoff = (ky * 16 + kx) * CIPAD + cib * 64;
    } else aoff = boff;
    u16* As = smem + buf * 16384;
    u16* Bs = As + 8192;
#pragma unroll
    for (int r = 0; r < 4; ++r) cp16(aSrc[r] + aoff, As + dstOff[r]);
#pragma unroll
    for (int r = 0; r < 4; ++r) cp16(bSrc[r] + boff, Bs + dstOff[r]);
  };

  const int tx = lane & 15, quad = lane >> 4, l7 = lane & 7;
  int rowA[4], rowB[4];
#pragma unroll
  for (int i = 0; i < 4; ++i) {
    rowA[i] = (wm * 64 + i * 16 + tx) * 64;
    rowB[i] = (wn * 64 + i * 16 + tx) * 64;
  }

  f32x4 acc[4][4];
#pragma unroll
  for (int i = 0; i < 4; ++i)
#pragma unroll
    for (int j = 0; j < 4; ++j) acc[i][j] = (f32x4){0.f, 0.f, 0.f, 0.f};

  // prologue: two stages in flight (16 outstanding loads per wave)
  stage(0, 0);
  stage(1, 1);
  int cur = 0;
  for (int kc = 0; kc < KCPB; ++kc) {
    // wait only for the OLDEST stage (8 loads); the newer 8 stay in flight
    if (kc + 1 < KCPB) { asm volatile("s_waitcnt vmcnt(8)" ::: "memory"); }
    else               { asm volatile("s_waitcnt vmcnt(0)" ::: "memory"); }
    BAR_MEM();                                // everyone's stage(kc) landed
    const u16* As = smem + cur * 16384;
    const u16* Bs = As + 8192;
#pragma unroll
    for (int ks = 0; ks < 2; ++ks) {
      int goff = (((ks * 4 + quad) ^ l7) << 3);
      bf16x8 af[4], bfr[4];
#pragma unroll
      for (int i = 0; i < 4; ++i) af[i] = *reinterpret_cast<const bf16x8*>(As + rowA[i] + goff);
#pragma unroll
      for (int i = 0; i < 4; ++i) bfr[i] = *reinterpret_cast<const bf16x8*>(Bs + rowB[i] + goff);
      __builtin_amdgcn_s_setprio(1);
#pragma unroll
      for (int i = 0; i < 4; ++i)
#pragma unroll
        for (int j = 0; j < 4; ++j)
          acc[i][j] = __builtin_amdgcn_mfma_f32_16x16x32_bf16(af[i], bfr[j], acc[i][j], 0, 0, 0);
      __builtin_amdgcn_s_setprio(0);
    }
    BAR_MEM();                                // all reads of cur retired
    if (kc + 2 < KCPB) stage(kc + 2, cur);    // overwrite just-freed buffer
    cur ^= 1;
  }

#pragma unroll
  for (int j = 0; j < 4; ++j) {
    int oc = oc0 + wn * 64 + j * 16 + tx;
    if (oc >= 540) continue;
    float bv = bias[oc];
#pragma unroll
    for (int i = 0; i < 4; ++i) {
      f32x4 v = acc[i][j];
      int px = px0 + wm * 64 + i * 16 + quad * 4;
      int n = px / 196, q2 = px - n * 196;    // 196 % 4 == 0: quad never crosses image
      size_t idx = ((size_t)(n * 540 + oc)) * 196 + q2;
      if constexpr (MODE == 0) {
        u16x4 mv;
#pragma unroll
        for (int r = 0; r < 4; ++r) {
          float val = fast_tanh(v[r] + bv);
          u16 vb = f2bf(val);
          mv[r] = vb;
          int qq = q2 + r;
          int y = qq / 14, x = qq - y * 14;
          git[((n * 16 + 1 + y) * 16 + 1 + x) * CIPAD + 540 + oc] = vb;
        }
        *reinterpret_cast<u16x4*>(marr + idx) = mv;    // 8B store, idx%4==0
      } else {
        u16x4 mv = *reinterpret_cast<const u16x4*>(marr + idx);
        f32x4 tv = *reinterpret_cast<const f32x4*>(tclip + idx);
        f32x4 res;
#pragma unroll
        for (int r = 0; r < 4; ++r) {
          res[r] = tv[r] + bf2f(mv[r]) * fast_sigmoid(v[r] + bv);
        }
        *reinterpret_cast<f32x4*>(outp + idx) = res;
      }
    }
  }
}

// ---------------- launcher ----------------
extern "C" void kernel_launch(void* const* d_in, const int* in_sizes, int n_in,
                              void* d_out, int out_size, void* d_ws, size_t ws_size,
                              hipStream_t stream)
{
  const float* frames = (const float*)d_in[0];
  const float* t_clip = (const float*)d_in[1];
  const float* w1 = (const float*)d_in[2];
  const float* b1 = (const float*)d_in[3];
  const float* w2 = (const float*)d_in[4];
  const float* b2 = (const float*)d_in[5];
  const float* wg = (const float*)d_in[6];
  const float* bg = (const float*)d_in[7];
  float* out = (float*)d_out;
  char* ws = (char*)d_ws;

  float* BSUM = (float*)(ws + OFF_BSUM);
  float* INVS = (float*)(ws + OFF_INVS);
  u16* HBF = (u16*)(ws + OFF_HBF);
  u16* GIT = (u16*)(ws + OFF_GIT);
  u16* WGB = (u16*)(ws + OFF_WGB);
  u16* W2B = (u16*)(ws + OFF_W2B);
  u16* MARR = (u16*)(ws + OFF_MARR);
  u16* HISTP = (u16*)(ws + OFF_HISTP);
  float* PSUM = (float*)(ws + OFF_PSUM);

  // merged prep: SWT (critical path, blocks first) + packs + halo + transpose.
  prep_kernel<<<SWT_BLOCKS + 6473, 256, 0, stream>>>(
      frames, wg, w2, t_clip, PSUM, HISTP, BSUM, WGB, W2B, GIT);

  quant_kernel<<<1920, 256, 0, stream>>>(HISTP, INVS);

  // MLP (epix fused into gemm1; tanh -> bf16 marr + git), then conv + gate -> out
  gemm1_kernel<<<dim3(196, 5), 256, 0, stream>>>(BSUM, PSUM, INVS, w1, b1, HBF);
  mfma_gemm_kernel<0><<<dim3(98, 5), 256, 0, stream>>>(HBF, W2B, b2, MARR, GIT, nullptr, nullptr);
  mfma_gemm_kernel<1><<<490, 256, 0, stream>>>(GIT, WGB, bg, MARR, nullptr, t_clip, out);
}